// Round 5
// baseline (648.423 us; speedup 1.0000x reference)
//
#include <hip/hip_runtime.h>
#include <hip/hip_bf16.h>

typedef short short8 __attribute__((ext_vector_type(8)));
typedef float f32x4 __attribute__((ext_vector_type(4)));
typedef float f32x2 __attribute__((ext_vector_type(2)));
typedef unsigned short u16;
typedef unsigned int u32;
typedef u32 u32x4 __attribute__((ext_vector_type(4)));

#define NL_STRIDE 57344
#define OFF_W1F 0
#define OFF_W2F 16384
#define OFF_W3F 49152
#define OFF_W1K 53248
#define OFF_B1  54272
#define OFF_B2  54784
#define OFF_B3  55296
#define OFF_W1KRAW 56320   // 256 floats: w1kraw[2n+r] = W1[r][n] (logical n)

__device__ __forceinline__ u16 f2bf(float f) {
  union { float f; unsigned int u; } v; v.f = f;
  unsigned int r = v.u + 0x7fffu + ((v.u >> 16) & 1u);
  return (u16)(r >> 16);
}

// pack two fp32 -> dword of 2 bf16 (round-half-up): a low, b high
__device__ __forceinline__ u32 pack_bf16_2(float a, float b) {
  union { float f; u32 u; } x, y; x.f = a; y.f = b;
  u32 ra = x.u + 0x8000u, rb = y.u + 0x8000u;
  return (ra >> 16) | (rb & 0xffff0000u);
}

// GELU pair; polynomial Phi-fit, max |err| ~6e-3 vs exact erf-GELU.
__device__ __forceinline__ f32x2 gelu2(f32x2 x) {
  f32x2 u = x * x;
  f32x2 t = u * 0.00417617f + (-0.0560330f);
  t = t * u + 0.394326f;
  f32x2 s = x * t + 0.5f;
  s.x = __builtin_amdgcn_fmed3f(s.x, 0.0f, 1.0f);
  s.y = __builtin_amdgcn_fmed3f(s.y, 0.0f, 1.0f);
  return x * s;
}

// hid column-pair permutation: u16 position p within a 32-block holds logical col
// (p>>1) | ((p&1)<<4)  (cols c and c+16 adjacent -> packed u32 epilogue writes).
__device__ __forceinline__ int kperm(int k) {
  int b = k & 31;
  return (k & ~31) | ((b >> 1) | ((b & 1) << 4));
}

// ---------------- prep: swizzle fp32 weights -> bf16 MFMA B-fragment order in ws ----
// B-frag (16x16x32 bf16), tile (kt,nt): lane l holds B[kt*32+(l>>4)*8+j][nt*16+(l&15)],
// flat elem = (kt*NT+nt)*512 + l*8 + j.  W2/W3 K-dims and B1/B2 are kperm'd.
__global__ __launch_bounds__(256) void prep_kernel(
    const float* __restrict__ sW1, const float* __restrict__ sb1,
    const float* __restrict__ sW2, const float* __restrict__ sb2,
    const float* __restrict__ sW3, const float* __restrict__ sb3,
    const float* __restrict__ tW1, const float* __restrict__ tb1,
    const float* __restrict__ tW2, const float* __restrict__ tb2,
    const float* __restrict__ tW3, const float* __restrict__ tb3,
    char* __restrict__ ws)
{
  int nl = blockIdx.x;               // 0..7 = layer*2 + net
  int layer = nl >> 1, net = nl & 1;
  const float* W1 = net ? tW1 : sW1;
  const float* W2 = net ? tW2 : sW2;
  const float* W3 = net ? tW3 : sW3;
  const float* B1 = net ? tb1 : sb1;
  const float* B2 = net ? tb2 : sb2;
  const float* B3 = net ? tb3 : sb3;
  char* base = ws + (size_t)nl * NL_STRIDE;
  int e = blockIdx.y * 256 + (int)threadIdx.x;

  if (e < 8192) {                                   // W1 (h-rows 2..65): K=64, N=128
    int kt = e >> 12, rem = e & 4095, nt = rem >> 9, r2 = rem & 511;
    int l = r2 >> 3, j = r2 & 7;
    int k = kt * 32 + (l >> 4) * 8 + j, n = nt * 16 + (l & 15);
    ((u16*)(base + OFF_W1F))[e] = f2bf(W1[layer * 8448 + (2 + k) * 128 + n]);
  } else if (e < 24576) {                           // W2: K=128 (kperm), N=128
    int e2 = e - 8192;
    int kt = e2 >> 12, nt = (e2 >> 9) & 7, l = (e2 >> 3) & 63, j = e2 & 7;
    int k = kt * 32 + (l >> 4) * 8 + j, n = nt * 16 + (l & 15);
    ((u16*)(base + OFF_W2F))[e2] = f2bf(W2[layer * 16384 + kperm(k) * 128 + n]);
  } else if (e < 26624) {                           // W3: K=128 (kperm), N padded 2->16
    int e3 = e - 24576;
    int kt = e3 >> 9, l = (e3 >> 3) & 63, j = e3 & 7;
    int k = kt * 32 + (l >> 4) * 8 + j, n = l & 15;
    float v = (n < 2) ? W3[layer * 256 + kperm(k) * 2 + n] : 0.0f;
    ((u16*)(base + OFF_W3F))[e3] = f2bf(v);
  } else if (e < 26880) {                           // legacy kperm'd W1K (unused now)
    int e4 = e - 26624; int r = e4 >> 7, n = e4 & 127;
    ((float*)(base + OFF_W1K))[e4] = W1[layer * 8448 + r * 128 + kperm(n)];
  } else if (e < 27008) {                           // b1, kperm
    int e5 = e - 26880; ((float*)(base + OFF_B1))[e5] = B1[layer * 128 + kperm(e5)];
  } else if (e < 27136) {                           // b2, kperm
    int e6 = e - 27008; ((float*)(base + OFF_B2))[e6] = B2[layer * 128 + kperm(e6)];
  } else if (e < 27138) {
    int e7 = e - 27136; ((float*)(base + OFF_B3))[e7] = B3[layer * 2 + e7];
  } else if (e < 27394) {                           // w1kraw[2n+r] = W1[r][n]
    int e8 = e - 27138; int n = e8 >> 1, r = e8 & 1;
    ((float*)(base + OFF_W1KRAW))[e8] = W1[layer * 8448 + r * 128 + n];
  }
}

// ---------------- main fused kernel: 128 rows/block, 512 threads (8 waves) ----------
// wave grid 2x4: mh = wave&1 owns rows [64*mh,64*mh+64); nq = wave>>1 owns n-tile
// pair {2nq,2nq+1}. Dual hid buffers; kt-block XOR swizzle: phys16dw = kt ^ (row&3).
__global__ __launch_bounds__(512, 4) void realnvp_kernel(
    const float* __restrict__ theta, const float* __restrict__ h_g,
    const char* __restrict__ ws, float* __restrict__ out)
{
  __shared__ __align__(16) u16 hidA[128 * 136];  // gelu1, bf16, pair-packed + swizzled
  __shared__ __align__(16) u16 hidB[128 * 136];  // gelu2
  __shared__ __align__(16) float x_lds[128 * 4];
  __shared__ float sbuf[2 * 128 * 2];

  const int tid = (int)threadIdx.x;
  const int row0 = (int)blockIdx.x * 128;
  const int wave = tid >> 6, lane = tid & 63, q = lane >> 4, lr = lane & 15;
  const int mh = wave & 1, nq = wave >> 1;
  u32* const hidAw = (u32*)hidA;
  u32* const hidBw = (u32*)hidB;

  // ---- stage theta -> x_lds
  if (tid < 128) {
    float4 t4 = *(const float4*)(theta + (size_t)(row0 + tid) * 4);
    x_lds[tid * 4 + 0] = t4.x; x_lds[tid * 4 + 1] = t4.y;
    x_lds[tid * 4 + 2] = t4.z; x_lds[tid * 4 + 3] = t4.w;
  }

  // ---- h A-fragments -> registers (wave rows 64mh+16i+lr; persist whole kernel)
  short8 hfr[4][2];
#pragma unroll
  for (int i = 0; i < 4; ++i)
#pragma unroll
    for (int kt = 0; kt < 2; ++kt) {
      const float* src = h_g + (size_t)(row0 + 64 * mh + 16 * i + lr) * 64 + kt * 32 + q * 8;
      float4 f0 = *(const float4*)(src);
      float4 f1 = *(const float4*)(src + 4);
      union { u32x4 u; short8 s; } cv;
      cv.u[0] = pack_bf16_2(f0.x, f0.y);
      cv.u[1] = pack_bf16_2(f0.z, f0.w);
      cv.u[2] = pack_bf16_2(f1.x, f1.y);
      cv.u[3] = pack_bf16_2(f1.z, f1.w);
      hfr[i][kt] = cv.s;
    }
  __syncthreads();

  float logdet = 0.0f;

#pragma unroll 1
  for (int layer = 0; layer < 4; ++layer) {
    const int k0 = (0x0210 >> (layer * 4)) & 15;   // KEEP[layer][0]
    const int k1 = (0x3321 >> (layer * 4)) & 15;   // KEEP[layer][1]

    // A2 frags (K-extension rows 64,65 = x[keep0], x[keep1]); same for s and t nets
    u32 a2[4];
#pragma unroll
    for (int i = 0; i < 4; ++i) {
      int row = 64 * mh + 16 * i + lr;
      float xa = x_lds[row * 4 + k0], xb = x_lds[row * 4 + k1];
      a2[i] = (q == 0) ? pack_bf16_2(xa, xb) : 0u;
    }

#pragma unroll 1
    for (int net = 0; net < 2; ++net) {
      const char* base = ws + (size_t)(layer * 2 + net) * NL_STRIDE;
      const u16* w1f = (const u16*)(base + OFF_W1F);
      const u16* w2f = (const u16*)(base + OFF_W2F);
      const u16* w3f = (const u16*)(base + OFF_W3F);
      const float* b1 = (const float*)(base + OFF_B1);
      const float* b2 = (const float*)(base + OFF_B2);
      const float* b3 = (const float*)(base + OFF_B3);
      const float* w1kraw = (const float*)(base + OFF_W1KRAW);

      // ============ GEMM1: acc = [h|x_keep] @ W1ext, bias via acc-init =============
      f32x4 acc[4][2];
      {
        f32x2 bb = *(const f32x2*)(b1 + nq * 32 + 2 * lr);
#pragma unroll
        for (int i = 0; i < 4; ++i) {
          acc[i][0] = (f32x4){bb.x, bb.x, bb.x, bb.x};
          acc[i][1] = (f32x4){bb.y, bb.y, bb.y, bb.y};
        }
        // kt2 B-frag: rows k=64,65 = W1 keep rows (only q==0, j=0,1 nonzero)
        f32x2 wr0 = *(const f32x2*)(w1kraw + 2 * (nq * 32 + lr));
        f32x2 wr1 = *(const f32x2*)(w1kraw + 2 * (nq * 32 + 16 + lr));
        union { u32x4 u; short8 s; } bx0, bx1;
        bx0.u = (u32x4){(q == 0) ? pack_bf16_2(wr0.x, wr0.y) : 0u, 0u, 0u, 0u};
        bx1.u = (u32x4){(q == 0) ? pack_bf16_2(wr1.x, wr1.y) : 0u, 0u, 0u, 0u};
#pragma unroll
        for (int kt = 0; kt < 2; ++kt) {
          short8 b0 = *(const short8*)(w1f + (kt * 8 + 2 * nq + 0) * 512 + lane * 8);
          short8 b1v = *(const short8*)(w1f + (kt * 8 + 2 * nq + 1) * 512 + lane * 8);
#pragma unroll
          for (int i = 0; i < 4; ++i) {
            acc[i][0] = __builtin_amdgcn_mfma_f32_16x16x32_bf16(hfr[i][kt], b0, acc[i][0], 0, 0, 0);
            acc[i][1] = __builtin_amdgcn_mfma_f32_16x16x32_bf16(hfr[i][kt], b1v, acc[i][1], 0, 0, 0);
          }
        }
#pragma unroll
        for (int i = 0; i < 4; ++i) {
          union { u32x4 u; short8 s; } ax;
          ax.u = (u32x4){a2[i], 0u, 0u, 0u};
          acc[i][0] = __builtin_amdgcn_mfma_f32_16x16x32_bf16(ax.s, bx0.s, acc[i][0], 0, 0, 0);
          acc[i][1] = __builtin_amdgcn_mfma_f32_16x16x32_bf16(ax.s, bx1.s, acc[i][1], 0, 0, 0);
        }
      }
      // ep1: gelu + pack + swizzled write -> hidA
#pragma unroll
      for (int i = 0; i < 4; ++i)
#pragma unroll
        for (int r = 0; r < 4; ++r) {
          int row = 64 * mh + 16 * i + 4 * q + r;     // row&3 == r
          f32x2 v = {acc[i][0][r], acc[i][1][r]};
          f32x2 g = gelu2(v);
          hidAw[row * 68 + ((nq ^ r) << 4) + lr] = pack_bf16_2(g.x, g.y);
        }
      __syncthreads();   // S1: hidA ready

      // ============ GEMM2: acc2 = gelu1 @ W2p, bias via acc-init ===================
      f32x4 acc2[4][2];
      {
        f32x2 cb = *(const f32x2*)(b2 + nq * 32 + 2 * lr);
#pragma unroll
        for (int i = 0; i < 4; ++i) {
          acc2[i][0] = (f32x4){cb.x, cb.x, cb.x, cb.x};
          acc2[i][1] = (f32x4){cb.y, cb.y, cb.y, cb.y};
        }
      }
#pragma unroll
      for (int kt = 0; kt < 4; ++kt) {
        short8 b0 = *(const short8*)(w2f + (kt * 8 + 2 * nq + 0) * 512 + lane * 8);
        short8 b1v = *(const short8*)(w2f + (kt * 8 + 2 * nq + 1) * 512 + lane * 8);
        const int kx = (kt ^ (lr & 3)) << 4;
#pragma unroll
        for (int i = 0; i < 4; ++i) {
          const short8 Ai = *(const short8*)(hidAw + (64 * mh + 16 * i + lr) * 68 + kx + q * 4);
          acc2[i][0] = __builtin_amdgcn_mfma_f32_16x16x32_bf16(Ai, b0, acc2[i][0], 0, 0, 0);
          acc2[i][1] = __builtin_amdgcn_mfma_f32_16x16x32_bf16(Ai, b1v, acc2[i][1], 0, 0, 0);
        }
      }
      // ep2: gelu + pack + swizzled write -> hidB (no barrier needed: different buffer)
#pragma unroll
      for (int i = 0; i < 4; ++i)
#pragma unroll
        for (int r = 0; r < 4; ++r) {
          int row = 64 * mh + 16 * i + 4 * q + r;
          f32x2 v = {acc2[i][0][r], acc2[i][1][r]};
          f32x2 g = gelu2(v);
          hidBw[row * 68 + ((nq ^ r) << 4) + lr] = pack_bf16_2(g.x, g.y);
        }
      __syncthreads();   // S3: hidB ready

      // ============ GEMM3: s/t = gelu2 @ W3p, b3 via acc-init ======================
      {
        float b3i = b3[lr & 1];
        f32x4 acc3 = (f32x4){b3i, b3i, b3i, b3i};
#pragma unroll
        for (int kt = 0; kt < 4; ++kt) {
          short8 b = *(const short8*)(w3f + kt * 512 + lane * 8);
          const short8 a = *(const short8*)(hidBw + (16 * wave + lr) * 68 + ((kt ^ (lr & 3)) << 4) + q * 4);
          acc3 = __builtin_amdgcn_mfma_f32_16x16x32_bf16(a, b, acc3, 0, 0, 0);
        }
        if (lr < 2) {
#pragma unroll
          for (int r = 0; r < 4; ++r)
            sbuf[net * 256 + (16 * wave + 4 * q + r) * 2 + lr] = acc3[r];
        }
      }
      __syncthreads();   // S4: sbuf ready, hidB reads done
    }  // net

    // ================= coupling update =================
    if (tid < 128) {
      float s0 = sbuf[tid * 2 + 0], s1 = sbuf[tid * 2 + 1];
      float t0 = sbuf[256 + tid * 2 + 0], t1 = sbuf[256 + tid * 2 + 1];
      const int a0 = (0x1002 >> (layer * 4)) & 15;   // TRANS[layer][0]
      const int a1 = (0x2133 >> (layer * 4)) & 15;   // TRANS[layer][1]
      x_lds[tid * 4 + a0] = x_lds[tid * 4 + a0] * __expf(s0) + t0;
      x_lds[tid * 4 + a1] = x_lds[tid * 4 + a1] * __expf(s1) + t1;
      logdet += s0 + s1;
    }
    __syncthreads();
  }  // layer

  if (tid < 128) {
    float x0 = x_lds[tid * 4 + 0], x1 = x_lds[tid * 4 + 1];
    float x2 = x_lds[tid * 4 + 2], x3 = x_lds[tid * 4 + 3];
    out[row0 + tid] = -0.5f * (x0 * x0 + x1 * x1 + x2 * x2 + x3 * x3)
                      - 3.6757541328f + logdet;
  }
}

extern "C" void kernel_launch(void* const* d_in, const int* in_sizes, int n_in,
                              void* d_out, int out_size, void* d_ws, size_t ws_size,
                              hipStream_t stream) {
  (void)in_sizes; (void)n_in; (void)out_size; (void)ws_size;
  const float* theta = (const float*)d_in[0];
  const float* h     = (const float*)d_in[1];
  const float* sW1 = (const float*)d_in[2],  *sb1 = (const float*)d_in[3];
  const float* sW2 = (const float*)d_in[4],  *sb2 = (const float*)d_in[5];
  const float* sW3 = (const float*)d_in[6],  *sb3 = (const float*)d_in[7];
  const float* tW1 = (const float*)d_in[8],  *tb1 = (const float*)d_in[9];
  const float* tW2 = (const float*)d_in[10], *tb2 = (const float*)d_in[11];
  const float* tW3 = (const float*)d_in[12], *tb3 = (const float*)d_in[13];
  float* out = (float*)d_out;
  char* ws = (char*)d_ws;

  dim3 pgrid(8, 108);   // 8 net-layers x ceil(27394/256)
  prep_kernel<<<pgrid, 256, 0, stream>>>(sW1, sb1, sW2, sb2, sW3, sb3,
                                         tW1, tb1, tW2, tb2, tW3, tb3, ws);
  realnvp_kernel<<<4096, 512, 0, stream>>>(theta, h, (const char*)ws, out);
}

// Round 6
// 647.306 us; speedup vs baseline: 1.0017x; 1.0017x over previous
//
#include <hip/hip_runtime.h>
#include <hip/hip_bf16.h>

typedef short short8 __attribute__((ext_vector_type(8)));
typedef float f32x4 __attribute__((ext_vector_type(4)));
typedef float f32x2 __attribute__((ext_vector_type(2)));
typedef unsigned short u16;
typedef unsigned int u32;
typedef u32 u32x4 __attribute__((ext_vector_type(4)));

#define NL_STRIDE 57344
#define OFF_W1F 0
#define OFF_W2F 16384
#define OFF_W3F 49152
#define OFF_W1K 53248
#define OFF_B1  54272
#define OFF_B2  54784
#define OFF_B3  55296
#define OFF_W1KRAW 56320   // 256 floats: w1kraw[2n+r] = W1[r][n] (logical n)

__device__ __forceinline__ u16 f2bf(float f) {
  union { float f; unsigned int u; } v; v.f = f;
  unsigned int r = v.u + 0x7fffu + ((v.u >> 16) & 1u);
  return (u16)(r >> 16);
}

// pack two fp32 -> dword of 2 bf16 (round-half-up): a low, b high
__device__ __forceinline__ u32 pack_bf16_2(float a, float b) {
  union { float f; u32 u; } x, y; x.f = a; y.f = b;
  u32 ra = x.u + 0x8000u, rb = y.u + 0x8000u;
  return (ra >> 16) | (rb & 0xffff0000u);
}

// GELU pair; polynomial Phi-fit, max |err| ~6e-3 vs exact erf-GELU.
__device__ __forceinline__ f32x2 gelu2(f32x2 x) {
  f32x2 u = x * x;
  f32x2 t = u * 0.00417617f + (-0.0560330f);
  t = t * u + 0.394326f;
  f32x2 s = x * t + 0.5f;
  s.x = __builtin_amdgcn_fmed3f(s.x, 0.0f, 1.0f);
  s.y = __builtin_amdgcn_fmed3f(s.y, 0.0f, 1.0f);
  return x * s;
}

// hid column-pair permutation: u16 position p within a 32-block holds logical col
// (p>>1) | ((p&1)<<4)  (cols c and c+16 adjacent -> packed u32 epilogue writes).
__device__ __forceinline__ int kperm(int k) {
  int b = k & 31;
  return (k & ~31) | ((b >> 1) | ((b & 1) << 4));
}

// ---------------- prep: swizzle fp32 weights -> bf16 MFMA B-fragment order in ws ----
// B-frag (16x16x32 bf16), tile (kt,nt): lane l holds B[kt*32+(l>>4)*8+j][nt*16+(l&15)],
// flat elem = (kt*NT+nt)*512 + l*8 + j.  W2/W3 K-dims and B1/B2 are kperm'd.
__global__ __launch_bounds__(256) void prep_kernel(
    const float* __restrict__ sW1, const float* __restrict__ sb1,
    const float* __restrict__ sW2, const float* __restrict__ sb2,
    const float* __restrict__ sW3, const float* __restrict__ sb3,
    const float* __restrict__ tW1, const float* __restrict__ tb1,
    const float* __restrict__ tW2, const float* __restrict__ tb2,
    const float* __restrict__ tW3, const float* __restrict__ tb3,
    char* __restrict__ ws)
{
  int nl = blockIdx.x;               // 0..7 = layer*2 + net
  int layer = nl >> 1, net = nl & 1;
  const float* W1 = net ? tW1 : sW1;
  const float* W2 = net ? tW2 : sW2;
  const float* W3 = net ? tW3 : sW3;
  const float* B1 = net ? tb1 : sb1;
  const float* B2 = net ? tb2 : sb2;
  const float* B3 = net ? tb3 : sb3;
  char* base = ws + (size_t)nl * NL_STRIDE;
  int e = blockIdx.y * 256 + (int)threadIdx.x;

  if (e < 8192) {                                   // W1 (h-rows 2..65): K=64, N=128
    int kt = e >> 12, rem = e & 4095, nt = rem >> 9, r2 = rem & 511;
    int l = r2 >> 3, j = r2 & 7;
    int k = kt * 32 + (l >> 4) * 8 + j, n = nt * 16 + (l & 15);
    ((u16*)(base + OFF_W1F))[e] = f2bf(W1[layer * 8448 + (2 + k) * 128 + n]);
  } else if (e < 24576) {                           // W2: K=128 (kperm), N=128
    int e2 = e - 8192;
    int kt = e2 >> 12, nt = (e2 >> 9) & 7, l = (e2 >> 3) & 63, j = e2 & 7;
    int k = kt * 32 + (l >> 4) * 8 + j, n = nt * 16 + (l & 15);
    ((u16*)(base + OFF_W2F))[e2] = f2bf(W2[layer * 16384 + kperm(k) * 128 + n]);
  } else if (e < 26624) {                           // W3: K=128 (kperm), N padded 2->16
    int e3 = e - 24576;
    int kt = e3 >> 9, l = (e3 >> 3) & 63, j = e3 & 7;
    int k = kt * 32 + (l >> 4) * 8 + j, n = l & 15;
    float v = (n < 2) ? W3[layer * 256 + kperm(k) * 2 + n] : 0.0f;
    ((u16*)(base + OFF_W3F))[e3] = f2bf(v);
  } else if (e < 26880) {                           // legacy kperm'd W1K (unused)
    int e4 = e - 26624; int r = e4 >> 7, n = e4 & 127;
    ((float*)(base + OFF_W1K))[e4] = W1[layer * 8448 + r * 128 + kperm(n)];
  } else if (e < 27008) {                           // b1, kperm
    int e5 = e - 26880; ((float*)(base + OFF_B1))[e5] = B1[layer * 128 + kperm(e5)];
  } else if (e < 27136) {                           // b2, kperm
    int e6 = e - 27008; ((float*)(base + OFF_B2))[e6] = B2[layer * 128 + kperm(e6)];
  } else if (e < 27138) {
    int e7 = e - 27136; ((float*)(base + OFF_B3))[e7] = B3[layer * 2 + e7];
  } else if (e < 27394) {                           // w1kraw[2n+r] = W1[r][n]
    int e8 = e - 27138; int n = e8 >> 1, r = e8 & 1;
    ((float*)(base + OFF_W1KRAW))[e8] = W1[layer * 8448 + r * 128 + n];
  }
}

// ---------------- main fused kernel: 128 rows/block, 512 threads (8 waves) ----------
// wave grid 2x4: mh = wave&1 owns rows [64*mh,64*mh+64); nq = wave>>1 owns n-tile
// pair {2nq,2nq+1}. Dual hid buffers; kt-block XOR swizzle: phys16dw = kt ^ (row&3).
// amdgpu_waves_per_eu(4,4): LDS already caps residency at 2 blocks/CU = 4 waves/EU;
// pinning max=4 stops the allocator from shrinking to 64 VGPRs (spill pathology of
// R3-R5 — __launch_bounds__'s 2nd arg sets only the MIN, allocator chased 8/EU).
__global__ __launch_bounds__(512)
__attribute__((amdgpu_waves_per_eu(4, 4)))
void realnvp_kernel(
    const float* __restrict__ theta, const float* __restrict__ h_g,
    const char* __restrict__ ws, float* __restrict__ out)
{
  __shared__ __align__(16) u16 hidA[128 * 136];  // gelu1, bf16, pair-packed + swizzled
  __shared__ __align__(16) u16 hidB[128 * 136];  // gelu2
  __shared__ __align__(16) float x_lds[128 * 4];
  __shared__ float sbuf[2 * 128 * 2];

  const int tid = (int)threadIdx.x;
  const int row0 = (int)blockIdx.x * 128;
  const int wave = tid >> 6, lane = tid & 63, q = lane >> 4, lr = lane & 15;
  const int mh = wave & 1, nq = wave >> 1;
  u32* const hidAw = (u32*)hidA;
  u32* const hidBw = (u32*)hidB;

  // ---- stage theta -> x_lds
  if (tid < 128) {
    float4 t4 = *(const float4*)(theta + (size_t)(row0 + tid) * 4);
    x_lds[tid * 4 + 0] = t4.x; x_lds[tid * 4 + 1] = t4.y;
    x_lds[tid * 4 + 2] = t4.z; x_lds[tid * 4 + 3] = t4.w;
  }

  // ---- h A-fragments -> registers (wave rows 64mh+16i+lr; persist whole kernel)
  short8 hfr[4][2];
#pragma unroll
  for (int i = 0; i < 4; ++i)
#pragma unroll
    for (int kt = 0; kt < 2; ++kt) {
      const float* src = h_g + (size_t)(row0 + 64 * mh + 16 * i + lr) * 64 + kt * 32 + q * 8;
      float4 f0 = *(const float4*)(src);
      float4 f1 = *(const float4*)(src + 4);
      union { u32x4 u; short8 s; } cv;
      cv.u[0] = pack_bf16_2(f0.x, f0.y);
      cv.u[1] = pack_bf16_2(f0.z, f0.w);
      cv.u[2] = pack_bf16_2(f1.x, f1.y);
      cv.u[3] = pack_bf16_2(f1.z, f1.w);
      hfr[i][kt] = cv.s;
    }
  __syncthreads();

  float logdet = 0.0f;

#pragma unroll 1
  for (int layer = 0; layer < 4; ++layer) {
    const int k0 = (0x0210 >> (layer * 4)) & 15;   // KEEP[layer][0]
    const int k1 = (0x3321 >> (layer * 4)) & 15;   // KEEP[layer][1]

    // A2 frags (K-extension rows 64,65 = x[keep0], x[keep1]); same for s and t nets
    u32 a2[4];
#pragma unroll
    for (int i = 0; i < 4; ++i) {
      int row = 64 * mh + 16 * i + lr;
      float xa = x_lds[row * 4 + k0], xb = x_lds[row * 4 + k1];
      a2[i] = (q == 0) ? pack_bf16_2(xa, xb) : 0u;
    }

#pragma unroll 1
    for (int net = 0; net < 2; ++net) {
      const char* base = ws + (size_t)(layer * 2 + net) * NL_STRIDE;
      const u16* w1f = (const u16*)(base + OFF_W1F);
      const u16* w2f = (const u16*)(base + OFF_W2F);
      const u16* w3f = (const u16*)(base + OFF_W3F);
      const float* b1 = (const float*)(base + OFF_B1);
      const float* b2 = (const float*)(base + OFF_B2);
      const float* b3 = (const float*)(base + OFF_B3);
      const float* w1kraw = (const float*)(base + OFF_W1KRAW);

      // ============ GEMM1: acc = [h|x_keep] @ W1ext, bias via acc-init =============
      f32x4 acc[4][2];
      {
        f32x2 bb = *(const f32x2*)(b1 + nq * 32 + 2 * lr);
#pragma unroll
        for (int i = 0; i < 4; ++i) {
          acc[i][0] = (f32x4){bb.x, bb.x, bb.x, bb.x};
          acc[i][1] = (f32x4){bb.y, bb.y, bb.y, bb.y};
        }
        // kt2 B-frag: rows k=64,65 = W1 keep rows (only q==0, j=0,1 nonzero)
        f32x2 wr0 = *(const f32x2*)(w1kraw + 2 * (nq * 32 + lr));
        f32x2 wr1 = *(const f32x2*)(w1kraw + 2 * (nq * 32 + 16 + lr));
        union { u32x4 u; short8 s; } bx0, bx1;
        bx0.u = (u32x4){(q == 0) ? pack_bf16_2(wr0.x, wr0.y) : 0u, 0u, 0u, 0u};
        bx1.u = (u32x4){(q == 0) ? pack_bf16_2(wr1.x, wr1.y) : 0u, 0u, 0u, 0u};
#pragma unroll
        for (int kt = 0; kt < 2; ++kt) {
          short8 b0 = *(const short8*)(w1f + (kt * 8 + 2 * nq + 0) * 512 + lane * 8);
          short8 b1v = *(const short8*)(w1f + (kt * 8 + 2 * nq + 1) * 512 + lane * 8);
#pragma unroll
          for (int i = 0; i < 4; ++i) {
            acc[i][0] = __builtin_amdgcn_mfma_f32_16x16x32_bf16(hfr[i][kt], b0, acc[i][0], 0, 0, 0);
            acc[i][1] = __builtin_amdgcn_mfma_f32_16x16x32_bf16(hfr[i][kt], b1v, acc[i][1], 0, 0, 0);
          }
        }
#pragma unroll
        for (int i = 0; i < 4; ++i) {
          union { u32x4 u; short8 s; } ax;
          ax.u = (u32x4){a2[i], 0u, 0u, 0u};
          acc[i][0] = __builtin_amdgcn_mfma_f32_16x16x32_bf16(ax.s, bx0.s, acc[i][0], 0, 0, 0);
          acc[i][1] = __builtin_amdgcn_mfma_f32_16x16x32_bf16(ax.s, bx1.s, acc[i][1], 0, 0, 0);
        }
      }
      // ep1: gelu + pack + swizzled write -> hidA
#pragma unroll
      for (int i = 0; i < 4; ++i)
#pragma unroll
        for (int r = 0; r < 4; ++r) {
          int row = 64 * mh + 16 * i + 4 * q + r;     // row&3 == r
          f32x2 v = {acc[i][0][r], acc[i][1][r]};
          f32x2 g = gelu2(v);
          hidAw[row * 68 + ((nq ^ r) << 4) + lr] = pack_bf16_2(g.x, g.y);
        }
      __syncthreads();   // S1: hidA ready

      // ============ GEMM2: acc2 = gelu1 @ W2p, bias via acc-init ===================
      f32x4 acc2[4][2];
      {
        f32x2 cb = *(const f32x2*)(b2 + nq * 32 + 2 * lr);
#pragma unroll
        for (int i = 0; i < 4; ++i) {
          acc2[i][0] = (f32x4){cb.x, cb.x, cb.x, cb.x};
          acc2[i][1] = (f32x4){cb.y, cb.y, cb.y, cb.y};
        }
      }
#pragma unroll
      for (int kt = 0; kt < 4; ++kt) {
        short8 b0 = *(const short8*)(w2f + (kt * 8 + 2 * nq + 0) * 512 + lane * 8);
        short8 b1v = *(const short8*)(w2f + (kt * 8 + 2 * nq + 1) * 512 + lane * 8);
        const int kx = (kt ^ (lr & 3)) << 4;
#pragma unroll
        for (int i = 0; i < 4; ++i) {
          const short8 Ai = *(const short8*)(hidAw + (64 * mh + 16 * i + lr) * 68 + kx + q * 4);
          acc2[i][0] = __builtin_amdgcn_mfma_f32_16x16x32_bf16(Ai, b0, acc2[i][0], 0, 0, 0);
          acc2[i][1] = __builtin_amdgcn_mfma_f32_16x16x32_bf16(Ai, b1v, acc2[i][1], 0, 0, 0);
        }
      }
      // ep2: gelu + pack + swizzled write -> hidB (different buffer, no barrier)
#pragma unroll
      for (int i = 0; i < 4; ++i)
#pragma unroll
        for (int r = 0; r < 4; ++r) {
          int row = 64 * mh + 16 * i + 4 * q + r;
          f32x2 v = {acc2[i][0][r], acc2[i][1][r]};
          f32x2 g = gelu2(v);
          hidBw[row * 68 + ((nq ^ r) << 4) + lr] = pack_bf16_2(g.x, g.y);
        }
      __syncthreads();   // S3: hidB ready

      // ============ GEMM3: s/t = gelu2 @ W3p, b3 via acc-init ======================
      {
        float b3i = b3[lr & 1];
        f32x4 acc3 = (f32x4){b3i, b3i, b3i, b3i};
#pragma unroll
        for (int kt = 0; kt < 4; ++kt) {
          short8 b = *(const short8*)(w3f + kt * 512 + lane * 8);
          const short8 a = *(const short8*)(hidBw + (16 * wave + lr) * 68 + ((kt ^ (lr & 3)) << 4) + q * 4);
          acc3 = __builtin_amdgcn_mfma_f32_16x16x32_bf16(a, b, acc3, 0, 0, 0);
        }
        if (lr < 2) {
#pragma unroll
          for (int r = 0; r < 4; ++r)
            sbuf[net * 256 + (16 * wave + 4 * q + r) * 2 + lr] = acc3[r];
        }
      }
      __syncthreads();   // S4: sbuf ready, hidB reads done
    }  // net

    // ================= coupling update =================
    if (tid < 128) {
      float s0 = sbuf[tid * 2 + 0], s1 = sbuf[tid * 2 + 1];
      float t0 = sbuf[256 + tid * 2 + 0], t1 = sbuf[256 + tid * 2 + 1];
      const int a0 = (0x1002 >> (layer * 4)) & 15;   // TRANS[layer][0]
      const int a1 = (0x2133 >> (layer * 4)) & 15;   // TRANS[layer][1]
      x_lds[tid * 4 + a0] = x_lds[tid * 4 + a0] * __expf(s0) + t0;
      x_lds[tid * 4 + a1] = x_lds[tid * 4 + a1] * __expf(s1) + t1;
      logdet += s0 + s1;
    }
    __syncthreads();
  }  // layer

  if (tid < 128) {
    float x0 = x_lds[tid * 4 + 0], x1 = x_lds[tid * 4 + 1];
    float x2 = x_lds[tid * 4 + 2], x3 = x_lds[tid * 4 + 3];
    out[row0 + tid] = -0.5f * (x0 * x0 + x1 * x1 + x2 * x2 + x3 * x3)
                      - 3.6757541328f + logdet;
  }
}

extern "C" void kernel_launch(void* const* d_in, const int* in_sizes, int n_in,
                              void* d_out, int out_size, void* d_ws, size_t ws_size,
                              hipStream_t stream) {
  (void)in_sizes; (void)n_in; (void)out_size; (void)ws_size;
  const float* theta = (const float*)d_in[0];
  const float* h     = (const float*)d_in[1];
  const float* sW1 = (const float*)d_in[2],  *sb1 = (const float*)d_in[3];
  const float* sW2 = (const float*)d_in[4],  *sb2 = (const float*)d_in[5];
  const float* sW3 = (const float*)d_in[6],  *sb3 = (const float*)d_in[7];
  const float* tW1 = (const float*)d_in[8],  *tb1 = (const float*)d_in[9];
  const float* tW2 = (const float*)d_in[10], *tb2 = (const float*)d_in[11];
  const float* tW3 = (const float*)d_in[12], *tb3 = (const float*)d_in[13];
  float* out = (float*)d_out;
  char* ws = (char*)d_ws;

  dim3 pgrid(8, 108);   // 8 net-layers x ceil(27394/256)
  prep_kernel<<<pgrid, 256, 0, stream>>>(sW1, sb1, sW2, sb2, sW3, sb3,
                                         tW1, tb1, tW2, tb2, tW3, tb3, ws);
  realnvp_kernel<<<4096, 512, 0, stream>>>(theta, h, (const char*)ws, out);
}